// Round 22
// baseline (27.907 us; speedup 1.0000x reference)
//
#include <hip/hip_runtime.h>
#include <hip/hip_bf16.h>

// B=64, N=8192. Output: concat(feats_final (B,N,2), feats_sparse (B,N,2)) f32.
// R22 = R21 (22.7 us) + LDS overlay: wt2c (11.3 KB) lives inside h1t's
// upper region (it is dead after the pre-loop wA2 register loads), cutting
// LDS ~61 -> ~50 KB => 3 blocks/CU (24 waves, launch_bounds(512,6)).
// Nothing else changes: same TSEG/NT/512 blocks/barrier structure/math.

#define BB 64
#define NN 8192
#define KWARM 8
#define TSEG 1024
#define H 8
#define PCH 8
#define NCH 130           // (TSEG+2H)/PCH
#define STG0 320
#define CHK 256
#define NT 512
#define HST 40            // 80 B rows: bank-quad(row)=5r%8 bijective
#define WT2OFF 2112       // ushort offset of wt2 staging region inside h1t
                          // (sa uses h1t[0..2112) ushorts = 4224 B)

using half8  = __attribute__((ext_vector_type(8))) _Float16;
using f32x16 = __attribute__((ext_vector_type(16))) float;

#define FENCE() asm volatile("" ::: "memory")

__device__ __forceinline__ half8 ld16(const ushort* p) {   // ds_read_b128
    return *reinterpret_cast<const half8*>(p);
}
__device__ __forceinline__ ushort f2h(float x) {
    _Float16 h = (_Float16)x;
    return __builtin_bit_cast(unsigned short, h);
}
__device__ __forceinline__ uint pk2rn(float a, float b) {  // 2x cvt RN + pack
    union { _Float16 h[2]; uint u; } r;
    r.h[0] = (_Float16)a; r.h[1] = (_Float16)b;
    return r.u;
}
__device__ __forceinline__ float h2f(ushort u) {
    return (float)__builtin_bit_cast(_Float16, u);
}

#define CSTV(RV, IV, AV) { float dd_ = RV*RV + IV*IV;                      \
    float iv_ = __builtin_amdgcn_rcpf(dd_);                                \
    float nr_ = -(AV) - RV*iv_;                                            \
    IV = 1.0f + IV*iv_; RV = nr_; }
#define GC(LRV, LIV, RRV, RIV, AV, MM, GR, GI) {                           \
    float Dr_ = LRV + RRV + (AV), Di_ = LIV + RIV - 1.0f;                  \
    float iv_ = __builtin_amdgcn_rcpf(Dr_*Dr_ + Di_*Di_);                  \
    GR = Dr_*iv_*(MM); GI = -Di_*iv_*(MM); }

__global__ __launch_bounds__(NT, 6) void fused_kernel(
    const float* __restrict__ v,  const float* __restrict__ mask,
    const float* __restrict__ w1, const float* __restrict__ b1,
    const float* __restrict__ w2, const float* __restrict__ b2,
    const float* __restrict__ w3, const float* __restrict__ b3,
    float* __restrict__ outF, float* __restrict__ fs)
{
    __shared__ __align__(16) ushort h1t[264 * HST];  // aliases sa + wt2 staging
    __shared__ __align__(16) ushort h2t[260 * HST];  // [row rel c-2][ci]
    __shared__ __align__(16) ushort wt1c[32 * 32];   // [co][k]; k10=bias
    __shared__ __align__(16) ushort wt3c[2 * 160];   // [co][k=kk*32+ci]
    __shared__ __align__(16) uint   xsp[TSEG + 2*H + 8];
    __shared__ __align__(8) unsigned char mskb[TSEG];
    __shared__ float b3s[2];

    const int tid  = threadIdx.x;
    const int b    = blockIdx.y;
    const int s    = blockIdx.x * TSEG;
    const int base = s - H - KWARM;

    float* sa = reinterpret_cast<float*>(h1t);       // phase-A alias (4224 B)

    for (int i = tid; i < TSEG + 2*H + 2*KWARM; i += NT) {
        int g = base + i; g = min(max(g, 0), NN - 1);
        sa[i] = v[b * NN + g] - 2.0f;
    }
    __syncthreads();

    // ---- phase A: chains (0..129) || xsp-pad zero || weight staging ----
    if (tid < NCH) {
        const int e0 = s - H + PCH * tid;            // e0 - base = 8*tid + KWARM
        if (e0 >= 0 && e0 + PCH <= NN) {
            float4 mva = *reinterpret_cast<const float4*>(&mask[b * NN + e0]);
            float4 mvb = *reinterpret_cast<const float4*>(&mask[b * NN + e0 + 4]);
            const float4* s4 = reinterpret_cast<const float4*>(sa);
            float4 aA = s4[2*tid + 2];               // a at idx 8t+8..11 (e0..e0+3)
            float4 aB = s4[2*tid + 3];               // a at idx 8t+12..15 (e0+4..e0+7)
            float Lr, Li, Rr, Ri;
            const bool fast = (e0 - KWARM >= 0) && (e0 + 7 + KWARM <= NN - 1);
            if (fast) {
                // interleaved 8+8-step warm, float4 reads, ILP=2
                float4 cL = s4[2*tid];               // idx 8t..8t+3
                float4 cR = s4[2*tid + 5];           // idx 8t+20..23
                Lr = -cL.x; Li = 1.0f; Rr = -cR.w; Ri = 1.0f;
                CSTV(Lr, Li, cL.y); CSTV(Rr, Ri, cR.z);
                CSTV(Lr, Li, cL.z); CSTV(Rr, Ri, cR.y);
                CSTV(Lr, Li, cL.w); CSTV(Rr, Ri, cR.x);
                {
                    float4 nL = s4[2*tid + 1];       // idx 8t+4..7
                    float4 nR = s4[2*tid + 4];       // idx 8t+16..19 (desc)
                    CSTV(Lr, Li, nL.x); CSTV(Rr, Ri, nR.w);
                    CSTV(Lr, Li, nL.y); CSTV(Rr, Ri, nR.z);
                    CSTV(Lr, Li, nL.z); CSTV(Rr, Ri, nR.y);
                    CSTV(Lr, Li, nL.w); CSTV(Rr, Ri, nR.x);
                }
                CSTV(Lr, Li, aA.x);                  // L at e0   (idx 8t+8)
                CSTV(Rr, Ri, aB.w);                  // R at e0+7 (idx 8t+15)
            } else {
                int j0 = max(e0 - KWARM, 0);
                Lr = -sa[j0 - base]; Li = 1.0f;
                for (int j = j0 + 1; j <= e0; ++j) CSTV(Lr, Li, sa[j - base]);
                int j1 = min(e0 + 7 + KWARM, NN - 1);
                Rr = -sa[j1 - base]; Ri = 1.0f;
                for (int j = j1 - 1; j >= e0 + 7; --j) CSTV(Rr, Ri, sa[j - base]);
            }
            // emit: L-ladder up, then R-ladder down with GC
            float L0r = Lr, L0i = Li;
            CSTV(Lr, Li, aA.y); float L1r = Lr, L1i = Li;
            CSTV(Lr, Li, aA.z); float L2r = Lr, L2i = Li;
            CSTV(Lr, Li, aA.w); float L3r = Lr, L3i = Li;
            CSTV(Lr, Li, aB.x); float L4r = Lr, L4i = Li;
            CSTV(Lr, Li, aB.y); float L5r = Lr, L5i = Li;
            CSTV(Lr, Li, aB.z); float L6r = Lr, L6i = Li;
            CSTV(Lr, Li, aB.w); float L7r = Lr, L7i = Li;
            float g0r,g0i,g1r,g1i,g2r,g2i,g3r,g3i,g4r,g4i,g5r,g5i,g6r,g6i,g7r,g7i;
            GC(L7r, L7i, Rr, Ri, aB.w, mvb.w, g7r, g7i);
            CSTV(Rr, Ri, aB.z); GC(L6r, L6i, Rr, Ri, aB.z, mvb.z, g6r, g6i);
            CSTV(Rr, Ri, aB.y); GC(L5r, L5i, Rr, Ri, aB.y, mvb.y, g5r, g5i);
            CSTV(Rr, Ri, aB.x); GC(L4r, L4i, Rr, Ri, aB.x, mvb.x, g4r, g4i);
            CSTV(Rr, Ri, aA.w); GC(L3r, L3i, Rr, Ri, aA.w, mva.w, g3r, g3i);
            CSTV(Rr, Ri, aA.z); GC(L2r, L2i, Rr, Ri, aA.z, mva.z, g2r, g2i);
            CSTV(Rr, Ri, aA.y); GC(L1r, L1i, Rr, Ri, aA.y, mva.y, g1r, g1i);
            CSTV(Rr, Ri, aA.x); GC(L0r, L0i, Rr, Ri, aA.x, mva.x, g0r, g0i);

            uint4 pkA, pkB;
            pkA.x = (uint)f2h(g0r) | ((uint)f2h(g0i) << 16);
            pkA.y = (uint)f2h(g1r) | ((uint)f2h(g1i) << 16);
            pkA.z = (uint)f2h(g2r) | ((uint)f2h(g2i) << 16);
            pkA.w = (uint)f2h(g3r) | ((uint)f2h(g3i) << 16);
            pkB.x = (uint)f2h(g4r) | ((uint)f2h(g4i) << 16);
            pkB.y = (uint)f2h(g5r) | ((uint)f2h(g5i) << 16);
            pkB.z = (uint)f2h(g6r) | ((uint)f2h(g6i) << 16);
            pkB.w = (uint)f2h(g7r) | ((uint)f2h(g7i) << 16);
            *reinterpret_cast<uint4*>(&xsp[PCH * tid])     = pkA;
            *reinterpret_cast<uint4*>(&xsp[PCH * tid + 4]) = pkB;

            if (e0 >= s && e0 < s + TSEG) {          // interior (non-halo)
                size_t off = ((size_t)b * NN + e0) * 2;
                *reinterpret_cast<float4*>(&fs[off])      = make_float4(g0r, g0i, g1r, g1i);
                *reinterpret_cast<float4*>(&fs[off + 4])  = make_float4(g2r, g2i, g3r, g3i);
                *reinterpret_cast<float4*>(&fs[off + 8])  = make_float4(g4r, g4i, g5r, g5i);
                *reinterpret_cast<float4*>(&fs[off + 12]) = make_float4(g6r, g6i, g7r, g7i);
                uint mb0 = (mva.x > 0.5f ? 1u : 0u) | (mva.y > 0.5f ? 1u : 0u) << 8
                         | (mva.z > 0.5f ? 1u : 0u) << 16 | (mva.w > 0.5f ? 1u : 0u) << 24;
                uint mb1 = (mvb.x > 0.5f ? 1u : 0u) | (mvb.y > 0.5f ? 1u : 0u) << 8
                         | (mvb.z > 0.5f ? 1u : 0u) << 16 | (mvb.w > 0.5f ? 1u : 0u) << 24;
                *reinterpret_cast<uint2*>(&mskb[e0 - s]) = make_uint2(mb0, mb1);
            }
        } else {
            uint4 z = {0u, 0u, 0u, 0u};
            *reinterpret_cast<uint4*>(&xsp[PCH * tid])     = z;
            *reinterpret_cast<uint4*>(&xsp[PCH * tid + 4]) = z;
        }
    } else if (tid < NCH + 8) {
        xsp[TSEG + 2*H + (tid - NCH)] = 0u;          // conv1 tail-tile pad
    } else if (tid >= STG0) {
        const int t0 = tid - STG0;                   // 192 staging threads
        // wt1c [co][32]: dst-indexed (small); k10 = bias, rest of k>=10 zero
        for (int i = t0; i < 1024; i += 192) {
            int co = i >> 5, k = i & 31;
            ushort val = 0;
            if (k < 10)       val = f2h(w1[co*10 + (k&1)*5 + (k>>1)]);
            else if (k == 10) val = f2h(b1[co]);
            wt1c[i] = val;
        }
        // wt2 staged INSIDE h1t at WT2OFF (disjoint from sa's 2112 ushorts).
        // SOURCE-linear (coalesced); src r=ci*5+kk -> dst k=(r%5)*32 + r/5.
        for (int i = t0; i < 5120; i += 192) {
            int co = i / 160, r = i - co*160;
            h1t[WT2OFF + co*176 + (r % 5)*32 + r/5] = f2h(w2[i]);
        }
        for (int i = t0; i < 512; i += 192) {
            int co = i >> 4, k = 160 + (i & 15);
            h1t[WT2OFF + co*176 + k] = (k == 160) ? f2h(b2[co]) : (ushort)0;
        }
        // wt3c [2][160]: source-linear; no bias slice (scalar add at store)
        for (int i = t0; i < 320; i += 192) {
            int co = i / 160, r = i - co*160;
            wt3c[co*160 + (r % 5)*32 + r/5] = f2h(w3[i]);
        }
        if (t0 < 2) b3s[t0] = b3[t0];
    }
    __syncthreads();
    // sa dead. wt2 region of h1t is live until the wA2 reads below.

    const int lane = tid & 63;
    const int wv   = tid >> 6;        // 0..7
    const int cn   = lane & 31;
    const int kh   = lane >> 5;
    const int kh4  = 4 * kh;

    // ones fragment in-register: k-slice {1,0,...} on kh=0 half (conv2 bias)
    union { half8 v8; uint u[4]; } on;
    on.u[0] = kh ? 0u : 0x3C00u; on.u[1] = 0u; on.u[2] = 0u; on.u[3] = 0u;
    const half8 onesF = on.v8;

    // persistent weight A-fragments (wA2 from the h1t overlay region)
    half8 wA1 = ld16(&wt1c[cn * 32 + 8 * kh]);   // includes bias at k=10
    half8 wA2[11];
    #pragma unroll
    for (int t = 0; t < 11; ++t)
        wA2[t] = ld16(&h1t[WT2OFF + cn*176 + 16*t + 8*kh]);
    const float bz0 = b3s[0], bz1 = b3s[1];
    __syncthreads();   // wt2 overlay dead; h1t fully reusable by conv1

    // per-tile bodies (identical math to R21)
    auto conv1_tile = [&](int cr, int tb1) {
        int mi = cr + 2 + tb1 + cn;
        union { half8 v8; uint u[4]; } B;
        if (kh == 0) { B.u[0]=xsp[mi];   B.u[1]=xsp[mi+1];
                       B.u[2]=xsp[mi+2]; B.u[3]=xsp[mi+3]; }
        else         { B.u[0]=xsp[mi+4]; B.u[1]=0x3C00u;   // k10=1.0
                       B.u[2]=0; B.u[3]=0; }
        f32x16 a1 = {};
        a1 = __builtin_amdgcn_mfma_f32_32x32x16_f16(wA1, B.v8, a1, 0, 0, 0);
        int row = tb1 + cn;
        int gp  = s + cr - 4 + row;
        bool ok = (gp >= 0) && (gp < NN);
        ushort* rp = &h1t[row * HST + kh4];
        #pragma unroll
        for (int q = 0; q < 4; ++q) {
            uint lo = pk2rn(fmaxf(a1[4*q+0], 0.f), fmaxf(a1[4*q+1], 0.f));
            uint hi = pk2rn(fmaxf(a1[4*q+2], 0.f), fmaxf(a1[4*q+3], 0.f));
            *reinterpret_cast<uint2*>(rp + 8*q) =
                make_uint2(ok ? lo : 0u, ok ? hi : 0u);
        }
    };
    auto conv2_tile = [&](int cr, int tb2) {
        f32x16 acc = {};
        #pragma unroll
        for (int q = 0; q < 10; ++q) {
            int kidx = 16*q + 8*kh;
            half8 Bf = ld16(&h1t[(tb2 + cn + (kidx >> 5))*HST + (kidx & 31)]);
            acc = __builtin_amdgcn_mfma_f32_32x32x16_f16(wA2[q], Bf, acc, 0, 0, 0);
        }
        acc = __builtin_amdgcn_mfma_f32_32x32x16_f16(wA2[10], onesF, acc, 0, 0, 0);
        int row = tb2 + cn;
        int gp  = s + cr - 2 + row;
        bool ok = (gp >= 0) && (gp < NN);
        ushort* rp = &h2t[row * HST + kh4];
        #pragma unroll
        for (int q = 0; q < 4; ++q) {
            uint lo = pk2rn(fmaxf(acc[4*q+0], 0.f), fmaxf(acc[4*q+1], 0.f));
            uint hi = pk2rn(fmaxf(acc[4*q+2], 0.f), fmaxf(acc[4*q+3], 0.f));
            *reinterpret_cast<uint2*>(rp + 8*q) =
                make_uint2(ok ? lo : 0u, ok ? hi : 0u);
        }
    };

    for (int ch = 0; ch < 4; ++ch) {
        const int cr = ch * CHK;

        // ---- conv1: ch==0: 9 tiles (wave0 serial tail); ch>=1: 8 tiles ----
        if (ch == 0) {
            conv1_tile(cr, 32 * wv);
            if (wv == 0) conv1_tile(cr, 232);
        } else {
            conv1_tile(cr, 8 + 32 * wv);             // rows 8..263 (4..7 copied)
        }
        __syncthreads();

        // ---- conv2: ch==0: 9 tiles (wave1 tail); ch>=1: 8 tiles ----
        if (ch == 0) {
            conv2_tile(cr, 32 * wv);
            if (wv == 1) conv2_tile(cr, 228);
        } else {
            conv2_tile(cr, 4 + 32 * wv);             // rows 4..259 (0..3 copied)
        }
        // h1 halo forward-copy for next chunk: rows 260..263 -> 4..7.
        // wave0 only; its own tile is the sole reader of rows 4..7 this
        // phase (same-wave order + fence); barriers publish to next chunk.
        if (ch < 3 && wv == 0 && lane < 40) {
            FENCE();
            int r = lane / 10, q = lane % 10;
            *reinterpret_cast<uint2*>(&h1t[(4 + r)*HST + 4*q]) =
                *reinterpret_cast<const uint2*>(&h1t[(260 + r)*HST + 4*q]);
        }
        __syncthreads();

        // ---- conv3: 8 tiles; kh=0 lanes: +bias, mask-select, store ----
        {
            const int tb3 = 32 * wv;
            f32x16 a3 = {};
            half8 z = {};
            const int wb = ((cn < 2) ? cn : 0) * 160;
            #pragma unroll
            for (int q = 0; q < 10; ++q) {
                int kidx = 16*q + 8*kh;
                half8 Af = (cn < 2) ? ld16(&wt3c[wb + 16*q + 8*kh]) : z;
                half8 Bf = ld16(&h2t[(tb3 + cn + (kidx >> 5))*HST + (kidx & 31)]);
                a3 = __builtin_amdgcn_mfma_f32_32x32x16_f16(Af, Bf, a3, 0, 0, 0);
            }
            if (kh == 0) {
                int p = cr + tb3 + cn;
                uint xp = xsp[H + p];                // f16 fs pair at pos s+p
                bool m  = mskb[p] != 0;
                float ox = m ? h2f((ushort)(xp & 0xffffu)) : (a3[0] + bz0);
                float oy = m ? h2f((ushort)(xp >> 16))     : (a3[1] + bz1);
                *reinterpret_cast<float2*>(&outF[((size_t)b*NN + s + p)*2]) =
                    make_float2(ox, oy);
            }
        }
        // h2 halo forward-copy: rows 256..259 -> 0..3. wave0 only (sole
        // reader of rows 0..3 in conv3); visible to next conv3 via the
        // conv1/conv2 barriers of the next chunk.
        if (ch < 3 && wv == 0 && lane < 40) {
            FENCE();
            int r = lane / 10, q = lane % 10;
            *reinterpret_cast<uint2*>(&h2t[r*HST + 4*q]) =
                *reinterpret_cast<const uint2*>(&h2t[(256 + r)*HST + 4*q]);
        }
        // no barrier: next conv1 writes h1t rows >=8 only; its barrier
        // orders h2t reuse (as in R21).
    }
}

extern "C" void kernel_launch(void* const* d_in, const int* in_sizes, int n_in,
                              void* d_out, int out_size, void* d_ws, size_t ws_size,
                              hipStream_t stream) {
    const float* v    = (const float*)d_in[0];
    const float* mask = (const float*)d_in[1];
    const float* w1   = (const float*)d_in[2];
    const float* b1   = (const float*)d_in[3];
    const float* w2   = (const float*)d_in[4];
    const float* b2   = (const float*)d_in[5];
    const float* w3   = (const float*)d_in[6];
    const float* b3   = (const float*)d_in[7];

    float* outF = (float*)d_out;                  // feats_final (B,N,2)
    float* fs   = outF + (size_t)BB * NN * 2;     // feats_sparse (B,N,2)

    dim3 g(NN / TSEG, BB);                        // 8 x 64 = 512 blocks
    fused_kernel<<<g, NT, 0, stream>>>(v, mask, w1, b1, w2, b2, w3, b3, outF, fs);
}

// Round 23
// 22.706 us; speedup vs baseline: 1.2291x; 1.2291x over previous
//
#include <hip/hip_runtime.h>
#include <hip/hip_bf16.h>

// B=64, N=8192. Output: concat(feats_final (B,N,2), feats_sparse (B,N,2)) f32.
// R23 = exact revert to R21 (22.7 us measured optimum): TSEG=1024, NT=512,
// KWARM=8, halo-reuse ring, coalesced weight staging, bias-folded MFMA,
// RN packing, launch_bounds(512,4). R22's occupancy overlay regressed and
// is dropped; this is the final configuration.

#define BB 64
#define NN 8192
#define KWARM 8
#define TSEG 1024
#define H 8
#define PCH 8
#define NCH 130           // (TSEG+2H)/PCH
#define STG0 320
#define CHK 256
#define NT 512
#define HST 40            // 80 B rows: bank-quad(row)=5r%8 bijective

using half8  = __attribute__((ext_vector_type(8))) _Float16;
using f32x16 = __attribute__((ext_vector_type(16))) float;

#define FENCE() asm volatile("" ::: "memory")

__device__ __forceinline__ half8 ld16(const ushort* p) {   // ds_read_b128
    return *reinterpret_cast<const half8*>(p);
}
__device__ __forceinline__ ushort f2h(float x) {
    _Float16 h = (_Float16)x;
    return __builtin_bit_cast(unsigned short, h);
}
__device__ __forceinline__ uint pk2rn(float a, float b) {  // 2x cvt RN + pack
    union { _Float16 h[2]; uint u; } r;
    r.h[0] = (_Float16)a; r.h[1] = (_Float16)b;
    return r.u;
}
__device__ __forceinline__ float h2f(ushort u) {
    return (float)__builtin_bit_cast(_Float16, u);
}

#define CSTV(RV, IV, AV) { float dd_ = RV*RV + IV*IV;                      \
    float iv_ = __builtin_amdgcn_rcpf(dd_);                                \
    float nr_ = -(AV) - RV*iv_;                                            \
    IV = 1.0f + IV*iv_; RV = nr_; }
#define GC(LRV, LIV, RRV, RIV, AV, MM, GR, GI) {                           \
    float Dr_ = LRV + RRV + (AV), Di_ = LIV + RIV - 1.0f;                  \
    float iv_ = __builtin_amdgcn_rcpf(Dr_*Dr_ + Di_*Di_);                  \
    GR = Dr_*iv_*(MM); GI = -Di_*iv_*(MM); }

__global__ __launch_bounds__(NT, 4) void fused_kernel(
    const float* __restrict__ v,  const float* __restrict__ mask,
    const float* __restrict__ w1, const float* __restrict__ b1,
    const float* __restrict__ w2, const float* __restrict__ b2,
    const float* __restrict__ w3, const float* __restrict__ b3,
    float* __restrict__ outF, float* __restrict__ fs)
{
    __shared__ __align__(16) ushort h1t[264 * HST];  // [row rel c-4][ci]; aliases sa
    __shared__ __align__(16) ushort h2t[260 * HST];  // [row rel c-2][ci]
    __shared__ __align__(16) ushort wt1c[32 * 32];   // [co][k]; k10=bias
    __shared__ __align__(16) ushort wt2c[32 * 176];  // [co][k=kk*32+ci]; k160=bias
    __shared__ __align__(16) ushort wt3c[2 * 160];   // [co][k=kk*32+ci]
    __shared__ __align__(16) uint   xsp[TSEG + 2*H + 8];
    __shared__ __align__(8) unsigned char mskb[TSEG];
    __shared__ float b3s[2];

    const int tid  = threadIdx.x;
    const int b    = blockIdx.y;
    const int s    = blockIdx.x * TSEG;
    const int base = s - H - KWARM;

    float* sa = reinterpret_cast<float*>(h1t);       // phase-A alias (4224 B)

    for (int i = tid; i < TSEG + 2*H + 2*KWARM; i += NT) {
        int g = base + i; g = min(max(g, 0), NN - 1);
        sa[i] = v[b * NN + g] - 2.0f;
    }
    __syncthreads();

    // ---- phase A: chains (0..129) || xsp-pad zero || weight staging ----
    if (tid < NCH) {
        const int e0 = s - H + PCH * tid;            // e0 - base = 8*tid + KWARM
        if (e0 >= 0 && e0 + PCH <= NN) {
            float4 mva = *reinterpret_cast<const float4*>(&mask[b * NN + e0]);
            float4 mvb = *reinterpret_cast<const float4*>(&mask[b * NN + e0 + 4]);
            const float4* s4 = reinterpret_cast<const float4*>(sa);
            float4 aA = s4[2*tid + 2];               // a at idx 8t+8..11 (e0..e0+3)
            float4 aB = s4[2*tid + 3];               // a at idx 8t+12..15 (e0+4..e0+7)
            float Lr, Li, Rr, Ri;
            const bool fast = (e0 - KWARM >= 0) && (e0 + 7 + KWARM <= NN - 1);
            if (fast) {
                // interleaved 8+8-step warm, float4 reads, ILP=2
                float4 cL = s4[2*tid];               // idx 8t..8t+3
                float4 cR = s4[2*tid + 5];           // idx 8t+20..23
                Lr = -cL.x; Li = 1.0f; Rr = -cR.w; Ri = 1.0f;
                CSTV(Lr, Li, cL.y); CSTV(Rr, Ri, cR.z);
                CSTV(Lr, Li, cL.z); CSTV(Rr, Ri, cR.y);
                CSTV(Lr, Li, cL.w); CSTV(Rr, Ri, cR.x);
                {
                    float4 nL = s4[2*tid + 1];       // idx 8t+4..7
                    float4 nR = s4[2*tid + 4];       // idx 8t+16..19 (desc)
                    CSTV(Lr, Li, nL.x); CSTV(Rr, Ri, nR.w);
                    CSTV(Lr, Li, nL.y); CSTV(Rr, Ri, nR.z);
                    CSTV(Lr, Li, nL.z); CSTV(Rr, Ri, nR.y);
                    CSTV(Lr, Li, nL.w); CSTV(Rr, Ri, nR.x);
                }
                CSTV(Lr, Li, aA.x);                  // L at e0   (idx 8t+8)
                CSTV(Rr, Ri, aB.w);                  // R at e0+7 (idx 8t+15)
            } else {
                int j0 = max(e0 - KWARM, 0);
                Lr = -sa[j0 - base]; Li = 1.0f;
                for (int j = j0 + 1; j <= e0; ++j) CSTV(Lr, Li, sa[j - base]);
                int j1 = min(e0 + 7 + KWARM, NN - 1);
                Rr = -sa[j1 - base]; Ri = 1.0f;
                for (int j = j1 - 1; j >= e0 + 7; --j) CSTV(Rr, Ri, sa[j - base]);
            }
            // emit: L-ladder up, then R-ladder down with GC
            float L0r = Lr, L0i = Li;
            CSTV(Lr, Li, aA.y); float L1r = Lr, L1i = Li;
            CSTV(Lr, Li, aA.z); float L2r = Lr, L2i = Li;
            CSTV(Lr, Li, aA.w); float L3r = Lr, L3i = Li;
            CSTV(Lr, Li, aB.x); float L4r = Lr, L4i = Li;
            CSTV(Lr, Li, aB.y); float L5r = Lr, L5i = Li;
            CSTV(Lr, Li, aB.z); float L6r = Lr, L6i = Li;
            CSTV(Lr, Li, aB.w); float L7r = Lr, L7i = Li;
            float g0r,g0i,g1r,g1i,g2r,g2i,g3r,g3i,g4r,g4i,g5r,g5i,g6r,g6i,g7r,g7i;
            GC(L7r, L7i, Rr, Ri, aB.w, mvb.w, g7r, g7i);
            CSTV(Rr, Ri, aB.z); GC(L6r, L6i, Rr, Ri, aB.z, mvb.z, g6r, g6i);
            CSTV(Rr, Ri, aB.y); GC(L5r, L5i, Rr, Ri, aB.y, mvb.y, g5r, g5i);
            CSTV(Rr, Ri, aB.x); GC(L4r, L4i, Rr, Ri, aB.x, mvb.x, g4r, g4i);
            CSTV(Rr, Ri, aA.w); GC(L3r, L3i, Rr, Ri, aA.w, mva.w, g3r, g3i);
            CSTV(Rr, Ri, aA.z); GC(L2r, L2i, Rr, Ri, aA.z, mva.z, g2r, g2i);
            CSTV(Rr, Ri, aA.y); GC(L1r, L1i, Rr, Ri, aA.y, mva.y, g1r, g1i);
            CSTV(Rr, Ri, aA.x); GC(L0r, L0i, Rr, Ri, aA.x, mva.x, g0r, g0i);

            uint4 pkA, pkB;
            pkA.x = (uint)f2h(g0r) | ((uint)f2h(g0i) << 16);
            pkA.y = (uint)f2h(g1r) | ((uint)f2h(g1i) << 16);
            pkA.z = (uint)f2h(g2r) | ((uint)f2h(g2i) << 16);
            pkA.w = (uint)f2h(g3r) | ((uint)f2h(g3i) << 16);
            pkB.x = (uint)f2h(g4r) | ((uint)f2h(g4i) << 16);
            pkB.y = (uint)f2h(g5r) | ((uint)f2h(g5i) << 16);
            pkB.z = (uint)f2h(g6r) | ((uint)f2h(g6i) << 16);
            pkB.w = (uint)f2h(g7r) | ((uint)f2h(g7i) << 16);
            *reinterpret_cast<uint4*>(&xsp[PCH * tid])     = pkA;
            *reinterpret_cast<uint4*>(&xsp[PCH * tid + 4]) = pkB;

            if (e0 >= s && e0 < s + TSEG) {          // interior (non-halo)
                size_t off = ((size_t)b * NN + e0) * 2;
                *reinterpret_cast<float4*>(&fs[off])      = make_float4(g0r, g0i, g1r, g1i);
                *reinterpret_cast<float4*>(&fs[off + 4])  = make_float4(g2r, g2i, g3r, g3i);
                *reinterpret_cast<float4*>(&fs[off + 8])  = make_float4(g4r, g4i, g5r, g5i);
                *reinterpret_cast<float4*>(&fs[off + 12]) = make_float4(g6r, g6i, g7r, g7i);
                uint mb0 = (mva.x > 0.5f ? 1u : 0u) | (mva.y > 0.5f ? 1u : 0u) << 8
                         | (mva.z > 0.5f ? 1u : 0u) << 16 | (mva.w > 0.5f ? 1u : 0u) << 24;
                uint mb1 = (mvb.x > 0.5f ? 1u : 0u) | (mvb.y > 0.5f ? 1u : 0u) << 8
                         | (mvb.z > 0.5f ? 1u : 0u) << 16 | (mvb.w > 0.5f ? 1u : 0u) << 24;
                *reinterpret_cast<uint2*>(&mskb[e0 - s]) = make_uint2(mb0, mb1);
            }
        } else {
            uint4 z = {0u, 0u, 0u, 0u};
            *reinterpret_cast<uint4*>(&xsp[PCH * tid])     = z;
            *reinterpret_cast<uint4*>(&xsp[PCH * tid + 4]) = z;
        }
    } else if (tid < NCH + 8) {
        xsp[TSEG + 2*H + (tid - NCH)] = 0u;          // conv1 tail-tile pad
    } else if (tid >= STG0) {
        const int t0 = tid - STG0;                   // 192 staging threads
        // wt1c [co][32]: dst-indexed (small); k10 = bias, rest of k>=10 zero
        for (int i = t0; i < 1024; i += 192) {
            int co = i >> 5, k = i & 31;
            ushort val = 0;
            if (k < 10)       val = f2h(w1[co*10 + (k&1)*5 + (k>>1)]);
            else if (k == 10) val = f2h(b1[co]);
            wt1c[i] = val;
        }
        // wt2c [co][176]: SOURCE-linear (coalesced reads); src r=ci*5+kk ->
        // dst k=(r%5)*32 + r/5. Pad k=160..175 filled by disjoint range.
        for (int i = t0; i < 5120; i += 192) {
            int co = i / 160, r = i - co*160;
            wt2c[co*176 + (r % 5)*32 + r/5] = f2h(w2[i]);
        }
        for (int i = t0; i < 512; i += 192) {
            int co = i >> 4, k = 160 + (i & 15);
            wt2c[co*176 + k] = (k == 160) ? f2h(b2[co]) : (ushort)0;
        }
        // wt3c [2][160]: source-linear; no bias slice (scalar add at store)
        for (int i = t0; i < 320; i += 192) {
            int co = i / 160, r = i - co*160;
            wt3c[co*160 + (r % 5)*32 + r/5] = f2h(w3[i]);
        }
        if (t0 < 2) b3s[t0] = b3[t0];
    }
    __syncthreads();
    // sa (aliased with h1t) dead from here.

    const int lane = tid & 63;
    const int wv   = tid >> 6;        // 0..7
    const int cn   = lane & 31;
    const int kh   = lane >> 5;
    const int kh4  = 4 * kh;

    // ones fragment in-register: k-slice {1,0,...} on kh=0 half (conv2 bias)
    union { half8 v8; uint u[4]; } on;
    on.u[0] = kh ? 0u : 0x3C00u; on.u[1] = 0u; on.u[2] = 0u; on.u[3] = 0u;
    const half8 onesF = on.v8;

    // persistent weight A-fragments (from LDS, loop-invariant)
    half8 wA1 = ld16(&wt1c[cn * 32 + 8 * kh]);   // includes bias at k=10
    half8 wA2[11];
    #pragma unroll
    for (int t = 0; t < 11; ++t) wA2[t] = ld16(&wt2c[cn*176 + 16*t + 8*kh]);
    const float bz0 = b3s[0], bz1 = b3s[1];

    // per-tile bodies (identical math to R19)
    auto conv1_tile = [&](int cr, int tb1) {
        int mi = cr + 2 + tb1 + cn;
        union { half8 v8; uint u[4]; } B;
        if (kh == 0) { B.u[0]=xsp[mi];   B.u[1]=xsp[mi+1];
                       B.u[2]=xsp[mi+2]; B.u[3]=xsp[mi+3]; }
        else         { B.u[0]=xsp[mi+4]; B.u[1]=0x3C00u;   // k10=1.0
                       B.u[2]=0; B.u[3]=0; }
        f32x16 a1 = {};
        a1 = __builtin_amdgcn_mfma_f32_32x32x16_f16(wA1, B.v8, a1, 0, 0, 0);
        int row = tb1 + cn;
        int gp  = s + cr - 4 + row;
        bool ok = (gp >= 0) && (gp < NN);
        ushort* rp = &h1t[row * HST + kh4];
        #pragma unroll
        for (int q = 0; q < 4; ++q) {
            uint lo = pk2rn(fmaxf(a1[4*q+0], 0.f), fmaxf(a1[4*q+1], 0.f));
            uint hi = pk2rn(fmaxf(a1[4*q+2], 0.f), fmaxf(a1[4*q+3], 0.f));
            *reinterpret_cast<uint2*>(rp + 8*q) =
                make_uint2(ok ? lo : 0u, ok ? hi : 0u);
        }
    };
    auto conv2_tile = [&](int cr, int tb2) {
        f32x16 acc = {};
        #pragma unroll
        for (int q = 0; q < 10; ++q) {
            int kidx = 16*q + 8*kh;
            half8 Bf = ld16(&h1t[(tb2 + cn + (kidx >> 5))*HST + (kidx & 31)]);
            acc = __builtin_amdgcn_mfma_f32_32x32x16_f16(wA2[q], Bf, acc, 0, 0, 0);
        }
        acc = __builtin_amdgcn_mfma_f32_32x32x16_f16(wA2[10], onesF, acc, 0, 0, 0);
        int row = tb2 + cn;
        int gp  = s + cr - 2 + row;
        bool ok = (gp >= 0) && (gp < NN);
        ushort* rp = &h2t[row * HST + kh4];
        #pragma unroll
        for (int q = 0; q < 4; ++q) {
            uint lo = pk2rn(fmaxf(acc[4*q+0], 0.f), fmaxf(acc[4*q+1], 0.f));
            uint hi = pk2rn(fmaxf(acc[4*q+2], 0.f), fmaxf(acc[4*q+3], 0.f));
            *reinterpret_cast<uint2*>(rp + 8*q) =
                make_uint2(ok ? lo : 0u, ok ? hi : 0u);
        }
    };

    for (int ch = 0; ch < 4; ++ch) {
        const int cr = ch * CHK;

        // ---- conv1: ch==0: 9 tiles (wave0 serial tail); ch>=1: 8 tiles ----
        if (ch == 0) {
            conv1_tile(cr, 32 * wv);
            if (wv == 0) conv1_tile(cr, 232);
        } else {
            conv1_tile(cr, 8 + 32 * wv);             // rows 8..263 (4..7 copied)
        }
        __syncthreads();

        // ---- conv2: ch==0: 9 tiles (wave1 tail); ch>=1: 8 tiles ----
        if (ch == 0) {
            conv2_tile(cr, 32 * wv);
            if (wv == 1) conv2_tile(cr, 228);
        } else {
            conv2_tile(cr, 4 + 32 * wv);             // rows 4..259 (0..3 copied)
        }
        // h1 halo forward-copy for next chunk: rows 260..263 -> 4..7.
        // wave0 only; its own tile is the sole reader of rows 4..7 this
        // phase (same-wave order + fence); barriers publish to next chunk.
        if (ch < 3 && wv == 0 && lane < 40) {
            FENCE();
            int r = lane / 10, q = lane % 10;
            *reinterpret_cast<uint2*>(&h1t[(4 + r)*HST + 4*q]) =
                *reinterpret_cast<const uint2*>(&h1t[(260 + r)*HST + 4*q]);
        }
        __syncthreads();

        // ---- conv3: 8 tiles; kh=0 lanes: +bias, mask-select, store ----
        {
            const int tb3 = 32 * wv;
            f32x16 a3 = {};
            half8 z = {};
            const int wb = ((cn < 2) ? cn : 0) * 160;
            #pragma unroll
            for (int q = 0; q < 10; ++q) {
                int kidx = 16*q + 8*kh;
                half8 Af = (cn < 2) ? ld16(&wt3c[wb + 16*q + 8*kh]) : z;
                half8 Bf = ld16(&h2t[(tb3 + cn + (kidx >> 5))*HST + (kidx & 31)]);
                a3 = __builtin_amdgcn_mfma_f32_32x32x16_f16(Af, Bf, a3, 0, 0, 0);
            }
            if (kh == 0) {
                int p = cr + tb3 + cn;
                uint xp = xsp[H + p];                // f16 fs pair at pos s+p
                bool m  = mskb[p] != 0;
                float ox = m ? h2f((ushort)(xp & 0xffffu)) : (a3[0] + bz0);
                float oy = m ? h2f((ushort)(xp >> 16))     : (a3[1] + bz1);
                *reinterpret_cast<float2*>(&outF[((size_t)b*NN + s + p)*2]) =
                    make_float2(ox, oy);
            }
        }
        // h2 halo forward-copy: rows 256..259 -> 0..3. wave0 only (sole
        // reader of rows 0..3 in conv3); visible to next conv3 via the
        // conv1/conv2 barriers of the next chunk.
        if (ch < 3 && wv == 0 && lane < 40) {
            FENCE();
            int r = lane / 10, q = lane % 10;
            *reinterpret_cast<uint2*>(&h2t[r*HST + 4*q]) =
                *reinterpret_cast<const uint2*>(&h2t[(256 + r)*HST + 4*q]);
        }
        // no barrier: next conv1 writes h1t rows >=8 only; its barrier
        // orders h2t reuse (as in R19).
    }
}

extern "C" void kernel_launch(void* const* d_in, const int* in_sizes, int n_in,
                              void* d_out, int out_size, void* d_ws, size_t ws_size,
                              hipStream_t stream) {
    const float* v    = (const float*)d_in[0];
    const float* mask = (const float*)d_in[1];
    const float* w1   = (const float*)d_in[2];
    const float* b1   = (const float*)d_in[3];
    const float* w2   = (const float*)d_in[4];
    const float* b2   = (const float*)d_in[5];
    const float* w3   = (const float*)d_in[6];
    const float* b3   = (const float*)d_in[7];

    float* outF = (float*)d_out;                  // feats_final (B,N,2)
    float* fs   = outF + (size_t)BB * NN * 2;     // feats_sparse (B,N,2)

    dim3 g(NN / TSEG, BB);                        // 8 x 64 = 512 blocks
    fused_kernel<<<g, NT, 0, stream>>>(v, mask, w1, b1, w2, b2, w3, b3, outF, fs);
}